// Round 5
// baseline (279.547 us; speedup 1.0000x reference)
//
#include <hip/hip_runtime.h>
#include <hip/hip_bf16.h>

// GCN encoder: 2x GCNConv (sym-norm, self-loops) + ReLU + row L2 normalize.
// N=50000, E=800000, IN=128, HID=256, OUT=256.
// Tiled MFMA bf16 GEMMs (A+B in LDS, fp32 accum), bf16 gather payload.

#define NNODE 50000
#define FDIM 256
#define SCAN_CHUNK 2048

typedef __attribute__((ext_vector_type(8))) short short8;   // 8 bf16 (4 VGPRs)
typedef __attribute__((ext_vector_type(4))) float f32x4;    // MFMA acc / vec store

__device__ __forceinline__ float bf2f(unsigned short u) {
    union { unsigned int i; float f; } c;
    c.i = ((unsigned int)u) << 16;
    return c.f;
}
__device__ __forceinline__ unsigned short f2bf(float f) {
    __hip_bfloat16 h = __float2bfloat16(f);  // RTN
    return *reinterpret_cast<unsigned short*>(&h);
}

// ---- CSR build ----------------------------------------------------------
__global__ void count_kernel(const int* __restrict__ ei, int* __restrict__ counts, int E) {
    int e = blockIdx.x * blockDim.x + threadIdx.x;
    if (e < E) atomicAdd(&counts[ei[E + e]], 1);
}

__global__ __launch_bounds__(256) void scan_part1(const int* __restrict__ counts,
                                                  int* __restrict__ bsum, int n) {
    __shared__ int ws[4];
    int b = blockIdx.x, t = threadIdx.x;
    int base = b * SCAN_CHUNK + t * 8;
    int s = 0;
#pragma unroll
    for (int j = 0; j < 8; ++j) {
        int i = base + j;
        if (i < n) s += counts[i];
    }
#pragma unroll
    for (int off = 32; off >= 1; off >>= 1) s += __shfl_xor(s, off, 64);
    if ((t & 63) == 0) ws[t >> 6] = s;
    __syncthreads();
    if (t == 0) bsum[b] = ws[0] + ws[1] + ws[2] + ws[3];
}

__global__ void scan_part2(const int* __restrict__ bsum, int* __restrict__ boff,
                           int* __restrict__ row_ptr, int nb, int n) {
    int l = threadIdx.x;
    int v = (l < nb) ? bsum[l] : 0;
    int incl = v;
#pragma unroll
    for (int off = 1; off < 64; off <<= 1) {
        int u = __shfl_up(incl, off, 64);
        if (l >= off) incl += u;
    }
    if (l < nb) boff[l] = incl - v;
    if (l == nb - 1) row_ptr[n] = incl;  // total == E
}

__global__ __launch_bounds__(256) void scan_part3(const int* __restrict__ counts,
                                                  const int* __restrict__ boff,
                                                  int* __restrict__ row_ptr,
                                                  int* __restrict__ cursor, int n) {
    __shared__ int ws[4];
    int b = blockIdx.x, t = threadIdx.x, lane = t & 63, wid = t >> 6;
    int base = b * SCAN_CHUNK + t * 8;
    int v[8];
    int s = 0;
#pragma unroll
    for (int j = 0; j < 8; ++j) {
        int i = base + j;
        v[j] = (i < n) ? counts[i] : 0;
        s += v[j];
    }
    int incl = s;
#pragma unroll
    for (int off = 1; off < 64; off <<= 1) {
        int u = __shfl_up(incl, off, 64);
        if (lane >= off) incl += u;
    }
    if (lane == 63) ws[wid] = incl;
    __syncthreads();
    int woff = 0;
    for (int u = 0; u < wid; ++u) woff += ws[u];
    int ex = boff[b] + woff + incl - s;
#pragma unroll
    for (int j = 0; j < 8; ++j) {
        int i = base + j;
        if (i < n) { row_ptr[i] = ex; cursor[i] = ex; }
        ex += v[j];
    }
}

__global__ void dinv_kernel(const int* __restrict__ counts, float* __restrict__ dinv, int n) {
    int i = blockIdx.x * blockDim.x + threadIdx.x;
    if (i < n) dinv[i] = rsqrtf((float)(counts[i] + 1));  // +1 self-loop
}

__global__ void fill_kernel(const int* __restrict__ ei, const float* __restrict__ dinv,
                            int* __restrict__ cursor, int2* __restrict__ edata, int E) {
    int e = blockIdx.x * blockDim.x + threadIdx.x;
    if (e < E) {
        int s = ei[e];
        int d = ei[E + e];
        int pos = atomicAdd(&cursor[d], 1);
        float nm = dinv[s] * dinv[d];
        edata[pos] = make_int2(s, __float_as_int(nm));
    }
}

// ---- W repack: Wf[g][col][j] = bf16(W[8g+j][col]), fragment-ready -------
template <int K>
__global__ void wconv_kernel(const float* __restrict__ W, unsigned short* __restrict__ Wf) {
    int idx = blockIdx.x * blockDim.x + threadIdx.x;  // (g, col)
    if (idx >= (K / 8) * 256) return;
    int g = idx >> 8, c = idx & 255;
    ushort4 lo = make_ushort4(f2bf(W[(8 * g + 0) * 256 + c]), f2bf(W[(8 * g + 1) * 256 + c]),
                              f2bf(W[(8 * g + 2) * 256 + c]), f2bf(W[(8 * g + 3) * 256 + c]));
    ushort4 hi = make_ushort4(f2bf(W[(8 * g + 4) * 256 + c]), f2bf(W[(8 * g + 5) * 256 + c]),
                              f2bf(W[(8 * g + 6) * 256 + c]), f2bf(W[(8 * g + 7) * 256 + c]));
    *reinterpret_cast<ushort4*>(&Wf[(size_t)idx * 8]) = lo;
    *reinterpret_cast<ushort4*>(&Wf[(size_t)idx * 8 + 4]) = hi;
}

// ---- Tiled MFMA GEMM: H[n,256] = bf16(X[n,K] @ W[K,256]) ----------------
// Block = 128 rows x 128 cols (grid.y = col-block), 4 waves in 2x2 of 64x64.
// As[row][gx][8]: gx = g ^ (row&7)  (conflict-free writes, 2-way-free reads)
// Bs[g][c][8]: fragment-grouped, linear (conflict-free both sides)
template <int K, typename T>
__global__ __launch_bounds__(256) void gemm_mfma(const T* __restrict__ X,
                                                 const unsigned short* __restrict__ Wf,
                                                 unsigned short* __restrict__ H, int n) {
    __shared__ unsigned short As[128 * K];
    __shared__ unsigned short Bs[(K / 8) * 128 * 8];
    int t = threadIdx.x;
    int row0 = blockIdx.x * 128;
    int cb = blockIdx.y;

    if constexpr (sizeof(T) == 4) {  // fp32 input (K=128): convert while staging
#pragma unroll
        for (int i = 0; i < (128 * K) / (4 * 256); ++i) {
            int o = 4 * (t + 256 * i);
            int row = o / K, k = o % K;
            int srow = row0 + row;
            float4 v = make_float4(0.f, 0.f, 0.f, 0.f);
            if (srow < n) v = *reinterpret_cast<const float4*>(&X[(size_t)srow * K + k]);
            ushort4 p = make_ushort4(f2bf(v.x), f2bf(v.y), f2bf(v.z), f2bf(v.w));
            int gx = (k >> 3) ^ (row & 7);
            *reinterpret_cast<ushort4*>(&As[row * K + gx * 8 + (k & 7)]) = p;
        }
    } else {  // bf16 input: straight copy
#pragma unroll
        for (int i = 0; i < (128 * K) / (8 * 256); ++i) {
            int o = 8 * (t + 256 * i);
            int row = o / K, k = o % K;
            int srow = row0 + row;
            uint4 v = make_uint4(0u, 0u, 0u, 0u);
            if (srow < n) v = *reinterpret_cast<const uint4*>(&X[(size_t)srow * K + k]);
            int gx = (k >> 3) ^ (row & 7);
            *reinterpret_cast<uint4*>(&As[row * K + gx * 8]) = v;
        }
    }
#pragma unroll
    for (int i = 0; i < ((K / 8) * 128) / 256; ++i) {
        int idx = t + 256 * i;
        int g = idx >> 7, c = idx & 127;
        *reinterpret_cast<uint4*>(&Bs[idx * 8]) =
            *reinterpret_cast<const uint4*>(&Wf[((size_t)g * 256 + cb * 128 + c) * 8]);
    }
    __syncthreads();

    int lane = t & 63, wv = t >> 6;
    int rw = wv >> 1, cw = wv & 1;
    int l15 = lane & 15, lhi = lane >> 4;
    f32x4 zero = {0.f, 0.f, 0.f, 0.f};
    f32x4 acc[4][4];
#pragma unroll
    for (int rf = 0; rf < 4; ++rf)
#pragma unroll
        for (int cf = 0; cf < 4; ++cf) acc[rf][cf] = zero;

#pragma unroll
    for (int s = 0; s < K / 32; ++s) {
        int g = 4 * s + lhi;
        short8 a[4], b[4];
#pragma unroll
        for (int rf = 0; rf < 4; ++rf) {
            int row = 64 * rw + 16 * rf + l15;
            a[rf] = *reinterpret_cast<const short8*>(&As[row * K + (g ^ (row & 7)) * 8]);
        }
#pragma unroll
        for (int cf = 0; cf < 4; ++cf) {
            int c = 64 * cw + 16 * cf + l15;
            b[cf] = *reinterpret_cast<const short8*>(&Bs[(g * 128 + c) * 8]);
        }
#pragma unroll
        for (int rf = 0; rf < 4; ++rf)
#pragma unroll
            for (int cf = 0; cf < 4; ++cf)
                acc[rf][cf] = __builtin_amdgcn_mfma_f32_16x16x32_bf16(a[rf], b[cf], acc[rf][cf], 0, 0, 0);
    }

#pragma unroll
    for (int rf = 0; rf < 4; ++rf)
#pragma unroll
        for (int cf = 0; cf < 4; ++cf) {
            f32x4 a = acc[rf][cf];
            int col = cb * 128 + 64 * cw + 16 * cf + l15;
#pragma unroll
            for (int j = 0; j < 4; ++j) {
                int row = row0 + 64 * rw + 16 * rf + 4 * lhi + j;
                if (row < n) H[(size_t)row * 256 + col] = f2bf(a[j]);
            }
        }
}

// ---- Aggregation, wave-per-node. Lane l owns features [4l, 4l+4). -------
__device__ __forceinline__ void agg_core(const unsigned short* __restrict__ hb,
                                         const int* __restrict__ rowp,
                                         const int2* __restrict__ edata,
                                         const float* __restrict__ dinv,
                                         const float* __restrict__ bias,
                                         int node, int lane,
                                         float& a0, float& a1, float& a2, float& a3) {
    float di = dinv[node];
    float d2 = di * di;
    ushort4 sv = *(reinterpret_cast<const ushort4*>(hb + (size_t)node * FDIM) + lane);
    float4 bv = *(reinterpret_cast<const float4*>(bias) + lane);
    a0 = fmaf(bf2f(sv.x), d2, bv.x);
    a1 = fmaf(bf2f(sv.y), d2, bv.y);
    a2 = fmaf(bf2f(sv.z), d2, bv.z);
    a3 = fmaf(bf2f(sv.w), d2, bv.w);
    int beg = rowp[node], end = rowp[node + 1];
#pragma unroll 4
    for (int e = beg; e < end; ++e) {
        int2 ed = edata[e];
        float nm = __int_as_float(ed.y);
        ushort4 v = *(reinterpret_cast<const ushort4*>(hb + (size_t)ed.x * FDIM) + lane);
        a0 = fmaf(bf2f(v.x), nm, a0);
        a1 = fmaf(bf2f(v.y), nm, a1);
        a2 = fmaf(bf2f(v.z), nm, a2);
        a3 = fmaf(bf2f(v.w), nm, a3);
    }
}

__global__ __launch_bounds__(256) void agg_relu_kernel(const unsigned short* __restrict__ hb,
                                                       const int* __restrict__ rowp,
                                                       const int2* __restrict__ edata,
                                                       const float* __restrict__ dinv,
                                                       const float* __restrict__ bias,
                                                       unsigned short* __restrict__ outB, int n) {
    int node = (blockIdx.x * blockDim.x + threadIdx.x) >> 6;
    int lane = threadIdx.x & 63;
    if (node >= n) return;
    float a0, a1, a2, a3;
    agg_core(hb, rowp, edata, dinv, bias, node, lane, a0, a1, a2, a3);
    ushort4 o = make_ushort4(f2bf(fmaxf(a0, 0.f)), f2bf(fmaxf(a1, 0.f)),
                             f2bf(fmaxf(a2, 0.f)), f2bf(fmaxf(a3, 0.f)));
    *(reinterpret_cast<ushort4*>(outB + (size_t)node * FDIM) + lane) = o;
}

__global__ __launch_bounds__(256) void agg_norm_kernel(const unsigned short* __restrict__ hb,
                                                       const int* __restrict__ rowp,
                                                       const int2* __restrict__ edata,
                                                       const float* __restrict__ dinv,
                                                       const float* __restrict__ bias,
                                                       float* __restrict__ out, int n) {
    int node = (blockIdx.x * blockDim.x + threadIdx.x) >> 6;
    int lane = threadIdx.x & 63;
    if (node >= n) return;
    float a0, a1, a2, a3;
    agg_core(hb, rowp, edata, dinv, bias, node, lane, a0, a1, a2, a3);
    float ss = a0 * a0 + a1 * a1 + a2 * a2 + a3 * a3;
#pragma unroll
    for (int off = 32; off >= 1; off >>= 1) ss += __shfl_xor(ss, off, 64);
    float rinv = 1.f / fmaxf(sqrtf(ss), 1e-12f);
    f32x4 o = {a0 * rinv, a1 * rinv, a2 * rinv, a3 * rinv};
    __builtin_nontemporal_store(o, reinterpret_cast<f32x4*>(out + (size_t)node * FDIM) + lane);
}

extern "C" void kernel_launch(void* const* d_in, const int* in_sizes, int n_in,
                              void* d_out, int out_size, void* d_ws, size_t ws_size,
                              hipStream_t stream) {
    const float* x  = (const float*)d_in[0];
    const int*   ei = (const int*)d_in[1];
    const float* W1 = (const float*)d_in[2];
    const float* b1 = (const float*)d_in[3];
    const float* W2 = (const float*)d_in[4];
    const float* b2 = (const float*)d_in[5];
    float* out = (float*)d_out;

    const int N = NNODE;
    const int E = in_sizes[1] / 2;
    const int NB = (N + SCAN_CHUNK - 1) / SCAN_CHUNK;

    char* ws = (char*)d_ws;
    size_t off = 0;
    auto alloc = [&](size_t bytes) -> void* {
        void* p = ws + off;
        off = (off + bytes + 255) & ~(size_t)255;
        return p;
    };
    unsigned short* Hbf = (unsigned short*)alloc((size_t)N * FDIM * 2);  // h1 then h2
    unsigned short* Bbf = (unsigned short*)alloc((size_t)N * FDIM * 2);  // relu(gcn1)
    unsigned short* Wf1 = (unsigned short*)alloc((size_t)(128 / 8) * 256 * 8 * 2);
    unsigned short* Wf2 = (unsigned short*)alloc((size_t)(256 / 8) * 256 * 8 * 2);
    int*   counts = (int*)alloc((size_t)N * 4);
    int*   rowp   = (int*)alloc((size_t)(N + 1) * 4);
    int*   cursor = (int*)alloc((size_t)N * 4);
    float* dinv   = (float*)alloc((size_t)N * 4);
    int2*  edata  = (int2*)alloc((size_t)E * 8);
    int*   bsum   = (int*)alloc((size_t)NB * 4);
    int*   boff   = (int*)alloc((size_t)NB * 4);

    wconv_kernel<128><<<(16 * 256 + 255) / 256, 256, 0, stream>>>(W1, Wf1);
    wconv_kernel<256><<<(32 * 256 + 255) / 256, 256, 0, stream>>>(W2, Wf2);

    hipMemsetAsync(counts, 0, (size_t)N * 4, stream);
    count_kernel<<<(E + 255) / 256, 256, 0, stream>>>(ei, counts, E);
    scan_part1<<<NB, 256, 0, stream>>>(counts, bsum, N);
    scan_part2<<<1, 64, 0, stream>>>(bsum, boff, rowp, NB, N);
    scan_part3<<<NB, 256, 0, stream>>>(counts, boff, rowp, cursor, N);
    dinv_kernel<<<(N + 255) / 256, 256, 0, stream>>>(counts, dinv, N);
    fill_kernel<<<(E + 255) / 256, 256, 0, stream>>>(ei, dinv, cursor, edata, E);

    dim3 ggrid((N + 127) / 128, 2);
    gemm_mfma<128, float><<<ggrid, 256, 0, stream>>>(x, Wf1, Hbf, N);
    agg_relu_kernel<<<(N * 64 + 255) / 256, 256, 0, stream>>>(Hbf, rowp, edata, dinv, b1, Bbf, N);
    gemm_mfma<256, unsigned short><<<ggrid, 256, 0, stream>>>(Bbf, Wf2, Hbf, N);
    agg_norm_kernel<<<(N * 64 + 255) / 256, 256, 0, stream>>>(Hbf, rowp, edata, dinv, b2, out, N);
}

// Round 6
// 253.068 us; speedup vs baseline: 1.1046x; 1.1046x over previous
//
#include <hip/hip_runtime.h>
#include <hip/hip_bf16.h>

// GCN encoder: 2x GCNConv (sym-norm, self-loops) + ReLU + row L2 normalize.
// N=50000, E=800000, IN=128, HID=256, OUT=256.
// MFMA bf16 GEMMs (A in LDS, B streamed), bf16 gather payload, 2-edge/wave agg.

#define NNODE 50000
#define FDIM 256
#define SCAN_CHUNK 2048

typedef __attribute__((ext_vector_type(8))) short short8;   // 8 bf16 (4 VGPRs)
typedef __attribute__((ext_vector_type(4))) float f32x4;    // MFMA acc / vec store

__device__ __forceinline__ float bf2f(unsigned short u) {
    union { unsigned int i; float f; } c;
    c.i = ((unsigned int)u) << 16;
    return c.f;
}
__device__ __forceinline__ float bflo(unsigned int u) {
    union { unsigned int i; float f; } c;
    c.i = u << 16;
    return c.f;
}
__device__ __forceinline__ float bfhi(unsigned int u) {
    union { unsigned int i; float f; } c;
    c.i = u & 0xFFFF0000u;
    return c.f;
}
__device__ __forceinline__ unsigned short f2bf(float f) {
    __hip_bfloat16 h = __float2bfloat16(f);  // RTN
    return *reinterpret_cast<unsigned short*>(&h);
}

// ---- CSR build ----------------------------------------------------------
__global__ void count_kernel(const int* __restrict__ ei, int* __restrict__ counts, int E) {
    int e = blockIdx.x * blockDim.x + threadIdx.x;
    if (e < E) atomicAdd(&counts[ei[E + e]], 1);
}

__global__ __launch_bounds__(256) void scan_part1(const int* __restrict__ counts,
                                                  int* __restrict__ bsum, int n) {
    __shared__ int ws[4];
    int b = blockIdx.x, t = threadIdx.x;
    int base = b * SCAN_CHUNK + t * 8;
    int s = 0;
#pragma unroll
    for (int j = 0; j < 8; ++j) {
        int i = base + j;
        if (i < n) s += counts[i];
    }
#pragma unroll
    for (int off = 32; off >= 1; off >>= 1) s += __shfl_xor(s, off, 64);
    if ((t & 63) == 0) ws[t >> 6] = s;
    __syncthreads();
    if (t == 0) bsum[b] = ws[0] + ws[1] + ws[2] + ws[3];
}

__global__ void scan_part2(const int* __restrict__ bsum, int* __restrict__ boff,
                           int* __restrict__ row_ptr, int nb, int n) {
    int l = threadIdx.x;
    int v = (l < nb) ? bsum[l] : 0;
    int incl = v;
#pragma unroll
    for (int off = 1; off < 64; off <<= 1) {
        int u = __shfl_up(incl, off, 64);
        if (l >= off) incl += u;
    }
    if (l < nb) boff[l] = incl - v;
    if (l == nb - 1) row_ptr[n] = incl;  // total == E
}

// part3 also produces dinv (fused; it already has counts in registers)
__global__ __launch_bounds__(256) void scan_part3(const int* __restrict__ counts,
                                                  const int* __restrict__ boff,
                                                  int* __restrict__ row_ptr,
                                                  int* __restrict__ cursor,
                                                  float* __restrict__ dinv, int n) {
    __shared__ int ws[4];
    int b = blockIdx.x, t = threadIdx.x, lane = t & 63, wid = t >> 6;
    int base = b * SCAN_CHUNK + t * 8;
    int v[8];
    int s = 0;
#pragma unroll
    for (int j = 0; j < 8; ++j) {
        int i = base + j;
        v[j] = (i < n) ? counts[i] : 0;
        s += v[j];
    }
    int incl = s;
#pragma unroll
    for (int off = 1; off < 64; off <<= 1) {
        int u = __shfl_up(incl, off, 64);
        if (lane >= off) incl += u;
    }
    if (lane == 63) ws[wid] = incl;
    __syncthreads();
    int woff = 0;
    for (int u = 0; u < wid; ++u) woff += ws[u];
    int ex = boff[b] + woff + incl - s;
#pragma unroll
    for (int j = 0; j < 8; ++j) {
        int i = base + j;
        if (i < n) {
            row_ptr[i] = ex;
            cursor[i] = ex;
            dinv[i] = rsqrtf((float)(v[j] + 1));  // +1 self-loop
        }
        ex += v[j];
    }
}

__global__ void fill_kernel(const int* __restrict__ ei, const float* __restrict__ dinv,
                            int* __restrict__ cursor, int2* __restrict__ edata, int E) {
    int e = blockIdx.x * blockDim.x + threadIdx.x;
    if (e < E) {
        int s = ei[e];
        int d = ei[E + e];
        int pos = atomicAdd(&cursor[d], 1);
        float nm = dinv[s] * dinv[d];
        edata[pos] = make_int2(s, __float_as_int(nm));
    }
}

// ---- W repack (both layers in one launch) -------------------------------
// Wf[g][col][j] = bf16(W[8g+j][col]), fragment-ready.
__global__ void wconv_kernel(const float* __restrict__ W1, unsigned short* __restrict__ Wf1,
                             const float* __restrict__ W2, unsigned short* __restrict__ Wf2) {
    int idx = blockIdx.x * blockDim.x + threadIdx.x;
    const float* W;
    unsigned short* Wf;
    if (idx < 16 * 256) {
        W = W1; Wf = Wf1;
    } else if (idx < (16 + 32) * 256) {
        idx -= 16 * 256;
        W = W2; Wf = Wf2;
    } else {
        return;
    }
    int g = idx >> 8, c = idx & 255;
    ushort4 lo = make_ushort4(f2bf(W[(8 * g + 0) * 256 + c]), f2bf(W[(8 * g + 1) * 256 + c]),
                              f2bf(W[(8 * g + 2) * 256 + c]), f2bf(W[(8 * g + 3) * 256 + c]));
    ushort4 hi = make_ushort4(f2bf(W[(8 * g + 4) * 256 + c]), f2bf(W[(8 * g + 5) * 256 + c]),
                              f2bf(W[(8 * g + 6) * 256 + c]), f2bf(W[(8 * g + 7) * 256 + c]));
    *reinterpret_cast<ushort4*>(&Wf[(size_t)idx * 8]) = lo;
    *reinterpret_cast<ushort4*>(&Wf[(size_t)idx * 8 + 4]) = hi;
}

// ---- MFMA GEMM: H[n,256] = bf16(X[n,K] @ W[K,256]) ----------------------
// BM=64, BN=256. 4 waves; wave w: rows[0,64) x cols[64w,64w+64).
// As[row][gx][8]: gx = g ^ (row&7); B streamed from Wf via L1/L2.
template <int K, typename T>
__global__ __launch_bounds__(256) void gemm_mfma(const T* __restrict__ X,
                                                 const unsigned short* __restrict__ Wf,
                                                 unsigned short* __restrict__ H, int n) {
    __shared__ unsigned short As[64 * K];
    int t = threadIdx.x;
    int row0 = blockIdx.x * 64;

    if constexpr (sizeof(T) == 4) {  // fp32 input (K=128): convert while staging
#pragma unroll
        for (int i = 0; i < (64 * K) / (4 * 256); ++i) {
            int o = 4 * (t + 256 * i);
            int row = o / K, k = o % K;
            int srow = row0 + row;
            float4 v = make_float4(0.f, 0.f, 0.f, 0.f);
            if (srow < n) v = *reinterpret_cast<const float4*>(&X[(size_t)srow * K + k]);
            ushort4 p = make_ushort4(f2bf(v.x), f2bf(v.y), f2bf(v.z), f2bf(v.w));
            int gx = (k >> 3) ^ (row & 7);
            *reinterpret_cast<ushort4*>(&As[row * K + gx * 8 + (k & 7)]) = p;
        }
    } else {  // bf16 input: straight copy
#pragma unroll
        for (int i = 0; i < (64 * K) / (8 * 256); ++i) {
            int o = 8 * (t + 256 * i);
            int row = o / K, k = o % K;
            int srow = row0 + row;
            uint4 v = make_uint4(0u, 0u, 0u, 0u);
            if (srow < n) v = *reinterpret_cast<const uint4*>(&X[(size_t)srow * K + k]);
            int gx = (k >> 3) ^ (row & 7);
            *reinterpret_cast<uint4*>(&As[row * K + gx * 8]) = v;
        }
    }
    __syncthreads();

    int lane = t & 63, wv = t >> 6;
    int l15 = lane & 15, lhi = lane >> 4;
    f32x4 zero = {0.f, 0.f, 0.f, 0.f};
    f32x4 acc[4][4];
#pragma unroll
    for (int rf = 0; rf < 4; ++rf)
#pragma unroll
        for (int cf = 0; cf < 4; ++cf) acc[rf][cf] = zero;

#pragma unroll
    for (int s = 0; s < K / 32; ++s) {
        int g = 4 * s + lhi;
        short8 a[4], b[4];
#pragma unroll
        for (int rf = 0; rf < 4; ++rf) {
            int row = 16 * rf + l15;
            a[rf] = *reinterpret_cast<const short8*>(&As[row * K + (g ^ (row & 7)) * 8]);
        }
#pragma unroll
        for (int cf = 0; cf < 4; ++cf) {
            int c = 64 * wv + 16 * cf + l15;
            b[cf] = *reinterpret_cast<const short8*>(&Wf[((size_t)g * 256 + c) * 8]);
        }
#pragma unroll
        for (int rf = 0; rf < 4; ++rf)
#pragma unroll
            for (int cf = 0; cf < 4; ++cf)
                acc[rf][cf] = __builtin_amdgcn_mfma_f32_16x16x32_bf16(a[rf], b[cf], acc[rf][cf], 0, 0, 0);
    }

#pragma unroll
    for (int rf = 0; rf < 4; ++rf)
#pragma unroll
        for (int cf = 0; cf < 4; ++cf) {
            f32x4 a = acc[rf][cf];
            int col = 64 * wv + 16 * cf + l15;
#pragma unroll
            for (int j = 0; j < 4; ++j) {
                int row = row0 + 16 * rf + 4 * lhi + j;
                if (row < n) H[(size_t)row * 256 + col] = f2bf(a[j]);
            }
        }
}

// ---- Aggregation: wave-per-node, 2 edges per iteration. -----------------
// Half h (lanes 32h..32h+31) handles edge e+h; lane owns 8 feats = 16B.
__device__ __forceinline__ void agg_core(const unsigned short* __restrict__ hb,
                                         const int* __restrict__ rowp,
                                         const int2* __restrict__ edata,
                                         const float* __restrict__ dinv,
                                         const float* __restrict__ bias,
                                         int node, int lane, float acc[8]) {
    int half = lane >> 5;
    int l31 = lane & 31;
    float di = dinv[node];
    float scale = half ? 0.f : 1.f;  // self+bias only in half 0 (combined later)
    float d2 = di * di * scale;
    uint4 sv = *(reinterpret_cast<const uint4*>(hb + (size_t)node * FDIM) + l31);
    float4 bv0 = *(reinterpret_cast<const float4*>(bias) + 2 * l31);
    float4 bv1 = *(reinterpret_cast<const float4*>(bias) + 2 * l31 + 1);
    acc[0] = fmaf(bflo(sv.x), d2, bv0.x * scale);
    acc[1] = fmaf(bfhi(sv.x), d2, bv0.y * scale);
    acc[2] = fmaf(bflo(sv.y), d2, bv0.z * scale);
    acc[3] = fmaf(bfhi(sv.y), d2, bv0.w * scale);
    acc[4] = fmaf(bflo(sv.z), d2, bv1.x * scale);
    acc[5] = fmaf(bfhi(sv.z), d2, bv1.y * scale);
    acc[6] = fmaf(bflo(sv.w), d2, bv1.z * scale);
    acc[7] = fmaf(bfhi(sv.w), d2, bv1.w * scale);
    int beg = rowp[node], end = rowp[node + 1];
#pragma unroll 2
    for (int e = beg; e < end; e += 2) {
        int ee = e + half;
        bool valid = ee < end;
        int2 ed = edata[valid ? ee : e];
        float nm = valid ? __int_as_float(ed.y) : 0.f;
        int src = valid ? ed.x : node;  // node row is L1-hot; nm=0 kills it
        uint4 v = *(reinterpret_cast<const uint4*>(hb + (size_t)src * FDIM) + l31);
        acc[0] = fmaf(bflo(v.x), nm, acc[0]);
        acc[1] = fmaf(bfhi(v.x), nm, acc[1]);
        acc[2] = fmaf(bflo(v.y), nm, acc[2]);
        acc[3] = fmaf(bfhi(v.y), nm, acc[3]);
        acc[4] = fmaf(bflo(v.z), nm, acc[4]);
        acc[5] = fmaf(bfhi(v.z), nm, acc[5]);
        acc[6] = fmaf(bflo(v.w), nm, acc[6]);
        acc[7] = fmaf(bfhi(v.w), nm, acc[7]);
    }
#pragma unroll
    for (int j = 0; j < 8; ++j) acc[j] += __shfl_xor(acc[j], 32, 64);
}

__global__ __launch_bounds__(256) void agg_relu_kernel(const unsigned short* __restrict__ hb,
                                                       const int* __restrict__ rowp,
                                                       const int2* __restrict__ edata,
                                                       const float* __restrict__ dinv,
                                                       const float* __restrict__ bias,
                                                       unsigned short* __restrict__ outB, int n) {
    int node = (blockIdx.x * blockDim.x + threadIdx.x) >> 6;
    int lane = threadIdx.x & 63;
    if (node >= n) return;
    float acc[8];
    agg_core(hb, rowp, edata, dinv, bias, node, lane, acc);
    int half = lane >> 5, l31 = lane & 63 & 31;
    int j0 = 4 * half;
    ushort4 o = make_ushort4(f2bf(fmaxf(acc[j0 + 0], 0.f)), f2bf(fmaxf(acc[j0 + 1], 0.f)),
                             f2bf(fmaxf(acc[j0 + 2], 0.f)), f2bf(fmaxf(acc[j0 + 3], 0.f)));
    *reinterpret_cast<ushort4*>(outB + (size_t)node * FDIM + l31 * 8 + j0) = o;
}

__global__ __launch_bounds__(256) void agg_norm_kernel(const unsigned short* __restrict__ hb,
                                                       const int* __restrict__ rowp,
                                                       const int2* __restrict__ edata,
                                                       const float* __restrict__ dinv,
                                                       const float* __restrict__ bias,
                                                       float* __restrict__ out, int n) {
    int node = (blockIdx.x * blockDim.x + threadIdx.x) >> 6;
    int lane = threadIdx.x & 63;
    if (node >= n) return;
    float acc[8];
    agg_core(hb, rowp, edata, dinv, bias, node, lane, acc);
    float ss = 0.f;
#pragma unroll
    for (int j = 0; j < 8; ++j) ss = fmaf(acc[j], acc[j], ss);
#pragma unroll
    for (int off = 16; off >= 1; off >>= 1) ss += __shfl_xor(ss, off, 64);  // within half
    float rinv = 1.f / fmaxf(sqrtf(ss), 1e-12f);
    int half = lane >> 5, l31 = lane & 31;
    int j0 = 4 * half;
    f32x4 o = {acc[j0 + 0] * rinv, acc[j0 + 1] * rinv, acc[j0 + 2] * rinv, acc[j0 + 3] * rinv};
    __builtin_nontemporal_store(o, reinterpret_cast<f32x4*>(out + (size_t)node * FDIM + l31 * 8 + j0));
}

extern "C" void kernel_launch(void* const* d_in, const int* in_sizes, int n_in,
                              void* d_out, int out_size, void* d_ws, size_t ws_size,
                              hipStream_t stream) {
    const float* x  = (const float*)d_in[0];
    const int*   ei = (const int*)d_in[1];
    const float* W1 = (const float*)d_in[2];
    const float* b1 = (const float*)d_in[3];
    const float* W2 = (const float*)d_in[4];
    const float* b2 = (const float*)d_in[5];
    float* out = (float*)d_out;

    const int N = NNODE;
    const int E = in_sizes[1] / 2;
    const int NB = (N + SCAN_CHUNK - 1) / SCAN_CHUNK;

    char* ws = (char*)d_ws;
    size_t off = 0;
    auto alloc = [&](size_t bytes) -> void* {
        void* p = ws + off;
        off = (off + bytes + 255) & ~(size_t)255;
        return p;
    };
    unsigned short* Hbf = (unsigned short*)alloc((size_t)N * FDIM * 2);  // h1 then h2
    unsigned short* Bbf = (unsigned short*)alloc((size_t)N * FDIM * 2);  // relu(gcn1)
    unsigned short* Wf1 = (unsigned short*)alloc((size_t)(128 / 8) * 256 * 8 * 2);
    unsigned short* Wf2 = (unsigned short*)alloc((size_t)(256 / 8) * 256 * 8 * 2);
    int*   counts = (int*)alloc((size_t)N * 4);
    int*   rowp   = (int*)alloc((size_t)(N + 1) * 4);
    int*   cursor = (int*)alloc((size_t)N * 4);
    float* dinv   = (float*)alloc((size_t)N * 4);
    int2*  edata  = (int2*)alloc((size_t)E * 8);
    int*   bsum   = (int*)alloc((size_t)NB * 4);
    int*   boff   = (int*)alloc((size_t)NB * 4);

    wconv_kernel<<<(48 * 256 + 255) / 256, 256, 0, stream>>>(W1, Wf1, W2, Wf2);

    hipMemsetAsync(counts, 0, (size_t)N * 4, stream);
    count_kernel<<<(E + 255) / 256, 256, 0, stream>>>(ei, counts, E);
    scan_part1<<<NB, 256, 0, stream>>>(counts, bsum, N);
    scan_part2<<<1, 64, 0, stream>>>(bsum, boff, rowp, NB, N);
    scan_part3<<<NB, 256, 0, stream>>>(counts, boff, rowp, cursor, dinv, N);
    fill_kernel<<<(E + 255) / 256, 256, 0, stream>>>(ei, dinv, cursor, edata, E);

    gemm_mfma<128, float><<<(N + 63) / 64, 256, 0, stream>>>(x, Wf1, Hbf, N);
    agg_relu_kernel<<<(N * 64 + 255) / 256, 256, 0, stream>>>(Hbf, rowp, edata, dinv, b1, Bbf, N);
    gemm_mfma<256, unsigned short><<<(N + 63) / 64, 256, 0, stream>>>(Bbf, Wf2, Hbf, N);
    agg_norm_kernel<<<(N * 64 + 255) / 256, 256, 0, stream>>>(Hbf, rowp, edata, dinv, b2, out, N);
}